// Round 8
// baseline (122.180 us; speedup 1.0000x reference)
//
#include <hip/hip_runtime.h>

#define THREADS 512
#define QPB 2            // queries per block
#define PPT 16           // points per thread = N / THREADS
#define KNN 32
#define CAP 448
#define MAXRETRY 33
#define NOTDONE 0xFFFFFFFFu

constexpr int Bc = 4, Nc = 8192, Sc = 2048, Cch = 64;

__device__ __forceinline__ unsigned dist2bits(float qx, float qy, float qz,
                                              float x, float y, float z) {
  // bit-exact vs numpy f32: no FMA contraction, fixed op order
  const float dx = __fsub_rn(qx, x);
  const float dy = __fsub_rn(qy, y);
  const float dz = __fsub_rn(qz, z);
  return __float_as_uint(__fadd_rn(
      __fadd_rn(__fmul_rn(dx, dx), __fmul_rn(dy, dy)), __fmul_rn(dz, dz)));
}

__global__ __launch_bounds__(THREADS, 4) void neighbor_group_kernel(
    const float* __restrict__ xyz,      // (B, N, 3)
    const float* __restrict__ new_xyz,  // (B, S, 3)
    const float* __restrict__ feat,     // (B, N, C)
    float* __restrict__ out)
{
  __shared__ unsigned candDb[QPB][CAP];
  __shared__ unsigned candIdx[QPB][CAP];
  __shared__ unsigned winIdx[QPB][KNN];
  __shared__ unsigned winDb[QPB][KNN];
  __shared__ unsigned wavePiv[8][QPB];
  __shared__ unsigned ccnt[QPB];
  __shared__ unsigned sPiv[QPB], sLo[QPB], sHi[QPB], sForce[QPB], sC[QPB];
  __shared__ unsigned sDone;

  const int tid  = threadIdx.x;
  const int lane = tid & 63;
  const int wid  = tid >> 6;            // 0..7
  const int q0   = blockIdx.x * QPB;
  const int b    = q0 >> 11;            // / S (S = 2048)

  const float qx0 = new_xyz[q0 * 3 + 0];
  const float qy0 = new_xyz[q0 * 3 + 1];
  const float qz0 = new_xyz[q0 * 3 + 2];
  const float qx1 = new_xyz[q0 * 3 + 3];
  const float qy1 = new_xyz[q0 * 3 + 4];
  const float qz1 = new_xyz[q0 * 3 + 5];

  const float4* __restrict__ xb4 = (const float4*)(xyz + (size_t)b * Nc * 3);

  // ---- single distance pass: keys in REGISTERS (16 pts x 2 queries) ----
  unsigned keys0[PPT], keys1[PPT];
  unsigned lmin0 = NOTDONE, lmin1 = NOTDONE;
#pragma unroll
  for (int j2 = 0; j2 < PPT / 4; ++j2) {   // 4 iterations
    const int g = tid + j2 * THREADS;      // group of 4 consecutive points
    const float4 f0 = xb4[3 * g + 0];
    const float4 f1 = xb4[3 * g + 1];
    const float4 f2 = xb4[3 * g + 2];
    const float px[4] = {f0.x, f0.w, f1.z, f2.y};
    const float py[4] = {f0.y, f1.x, f1.w, f2.z};
    const float pz[4] = {f0.z, f1.y, f2.x, f2.w};
#pragma unroll
    for (int k = 0; k < 4; ++k) {
      const unsigned k0 = dist2bits(qx0, qy0, qz0, px[k], py[k], pz[k]);
      const unsigned k1 = dist2bits(qx1, qy1, qz1, px[k], py[k], pz[k]);
      keys0[j2 * 4 + k] = k0;
      keys1[j2 * 4 + k] = k1;
      lmin0 = min(lmin0, k0);
      lmin1 = min(lmin1, k1);
    }
  }

  // ---- per-wave 4th-smallest of 64 thread-mins via bitwise ballot select ---
  // largest P with count(lmin < P) < 4; pivot = P+1 -> >=4/wave x 8 -> >=32
  {
    unsigned P0 = 0u, P1 = 0u;
#pragma unroll
    for (int bb = 30; bb >= 0; --bb) {
      const unsigned t0 = P0 | (1u << bb);
      const unsigned t1 = P1 | (1u << bb);
      if (__popcll(__ballot(lmin0 < t0)) < 4) P0 = t0;
      if (__popcll(__ballot(lmin1 < t1)) < 4) P1 = t1;
    }
    if (lane == 0) { wavePiv[wid][0] = P0 + 1u; wavePiv[wid][1] = P1 + 1u; }
  }
  if (tid < QPB) {
    ccnt[tid] = 0u;
    sLo[tid] = 0u; sHi[tid] = NOTDONE; sForce[tid] = 0u; sC[tid] = NOTDONE;
  }
  __syncthreads();
  if (tid < QPB) {
    unsigned p = wavePiv[0][tid];
#pragma unroll
    for (int w = 1; w < 8; ++w) p = max(p, wavePiv[w][tid]);
    sPiv[tid] = p;
  }

  // ---- compaction (register sweep); rare bisection retry on overflow ----
  for (int it = 0; it < MAXRETRY; ++it) {
    __syncthreads();
    const unsigned piv0 = (sC[0] == NOTDONE) ? sPiv[0] : 0u;
    const unsigned piv1 = (sC[1] == NOTDONE) ? sPiv[1] : 0u;
    if (tid == 0) sDone = 1u;
    __syncthreads();
#pragma unroll
    for (int j = 0; j < PPT; ++j) {
      // point index p = 4*tid + (j>>2)*2048 + (j&3)
      const unsigned pidx = (unsigned)(4 * tid + (j >> 2) * 2048 + (j & 3));
      if (keys0[j] < piv0) {
        const unsigned pos = atomicAdd(&ccnt[0], 1u);
        if (pos < CAP) { candDb[0][pos] = keys0[j]; candIdx[0][pos] = pidx; }
      }
      if (keys1[j] < piv1) {
        const unsigned pos = atomicAdd(&ccnt[1], 1u);
        if (pos < CAP) { candDb[1][pos] = keys1[j]; candIdx[1][pos] = pidx; }
      }
    }
    __syncthreads();
    if (tid < QPB && sC[tid] == NOTDONE) {
      const unsigned c = ccnt[tid];
      if (sForce[tid] || (c >= KNN && c <= CAP)) {
        sC[tid] = min(c, (unsigned)CAP);
      } else {
        if (c < KNN) sLo[tid] = sPiv[tid]; else sHi[tid] = sPiv[tid];
        if (sHi[tid] - sLo[tid] <= 1u) { sPiv[tid] = sHi[tid]; sForce[tid] = 1u; }
        else sPiv[tid] = sLo[tid] + ((sHi[tid] - sLo[tid]) >> 1);
        ccnt[tid] = 0u;
        sDone = 0u;
      }
    }
    __syncthreads();
    if (sDone) break;
  }

  const unsigned C0 = sC[0], C1 = sC[1];

  // ---- sqrt only candidates (numpy ranks use sqrt f32 bits + idx ties) ----
  for (unsigned t = tid; t < C0; t += THREADS)
    candDb[0][t] = __float_as_uint(__fsqrt_rn(__uint_as_float(candDb[0][t])));
  for (unsigned t = tid; t < C1; t += THREADS)
    candDb[1][t] = __float_as_uint(__fsqrt_rn(__uint_as_float(candDb[1][t])));
  __syncthreads();

  // ---- exact rank by (sqrt bits, idx); C <= 448 -> 1 candidate/thread ----
#pragma unroll
  for (int qi = 0; qi < QPB; ++qi) {
    const unsigned Cc = (qi == 0) ? C0 : C1;
    for (unsigned t = tid; t < Cc; t += THREADS) {
      const unsigned mdb = candDb[qi][t];
      const unsigned mix = candIdx[qi][t];
      unsigned rank = 0u;
      for (unsigned o = 0; o < Cc; ++o) {  // same addr across lanes: broadcast
        const unsigned odb = candDb[qi][o];
        const unsigned oix = candIdx[qi][o];
        rank += (odb < mdb || (odb == mdb && oix < mix)) ? 1u : 0u;
      }
      if (rank < KNN) { winIdx[qi][rank] = mix; winDb[qi][rank] = mdb; }
    }
  }
  __syncthreads();

  // ---- outputs (flat concat: nxyz | idxs | nfeat | values), all f32 ----
  float* out_nx = out;                                   // B*S*K*3
  float* out_id = out + (size_t)Bc * Sc * KNN * 3;       // B*S*K
  float* out_nf = out_id + (size_t)Bc * Sc * KNN;        // B*S*K*C
  float* out_sv = out_nf + (size_t)Bc * Sc * KNN * Cch;  // B*S*K

  const float* xb = xyz + (size_t)b * Nc * 3;
  const float4* fb4 = (const float4*)(feat + (size_t)b * Nc * Cch);

  if (tid < KNN * QPB) {                 // idx + value, both queries
    const int qi = tid >> 5, w = tid & 31;
    out_id[(size_t)(q0 + qi) * KNN + w] = (float)winIdx[qi][w];
    out_sv[(size_t)(q0 + qi) * KNN + w] = __uint_as_float(winDb[qi][w]);
  }
  if (tid < KNN * 3 * QPB) {             // neighbor xyz, both queries
    const int qi = tid / 96, r = tid % 96;
    const int w = r / 3, c3 = r % 3;
    out_nx[((size_t)(q0 + qi) * KNN + w) * 3 + c3] =
        xb[(size_t)winIdx[qi][w] * 3 + c3];
  }
  // feature gather: per query 32 winners x 16 float4 = 512 = THREADS
#pragma unroll
  for (int qi = 0; qi < QPB; ++qi) {
    float4* onf4 = (float4*)(out_nf + (size_t)(q0 + qi) * KNN * Cch);
    const int w = tid >> 4, c4 = tid & 15;
    onf4[w * 16 + c4] = fb4[(size_t)winIdx[qi][w] * 16 + c4];
  }
}

extern "C" void kernel_launch(void* const* d_in, const int* in_sizes, int n_in,
                              void* d_out, int out_size, void* d_ws, size_t ws_size,
                              hipStream_t stream) {
  const float* xyz     = (const float*)d_in[0];
  const float* new_xyz = (const float*)d_in[1];
  const float* feat    = (const float*)d_in[2];
  float* out = (float*)d_out;

  const int grid = (Bc * Sc) / QPB;  // 4096 blocks, 2 queries each
  neighbor_group_kernel<<<grid, THREADS, 0, stream>>>(xyz, new_xyz, feat, out);
}

// Round 9
// 86.446 us; speedup vs baseline: 1.4134x; 1.4134x over previous
//
#include <hip/hip_runtime.h>

#define THREADS 256
#define KNN 32
#define CAP 320
#define MAXRETRY 33

constexpr int Bc = 4, Nc = 8192, Sc = 2048, Cch = 64;

__device__ __forceinline__ unsigned dist2bits(float qx, float qy, float qz,
                                              float x, float y, float z) {
  // bit-exact vs numpy f32: no FMA contraction, fixed op order
  const float dx = __fsub_rn(qx, x);
  const float dy = __fsub_rn(qy, y);
  const float dz = __fsub_rn(qz, z);
  return __float_as_uint(__fadd_rn(
      __fadd_rn(__fmul_rn(dx, dx), __fmul_rn(dy, dy)), __fmul_rn(dz, dz)));
}

__global__ __launch_bounds__(THREADS, 4) void neighbor_group_kernel(
    const float* __restrict__ xyz,      // (B, N, 3)
    const float* __restrict__ new_xyz,  // (B, S, 3)
    const float* __restrict__ feat,     // (B, N, C)
    float* __restrict__ out)
{
  __shared__ unsigned candDb0[CAP], candIdx0[CAP];
  __shared__ unsigned candDb1[CAP], candIdx1[CAP];
  __shared__ unsigned winIdx0[KNN], winDb0[KNN];
  __shared__ unsigned winIdx1[KNN], winDb1[KNN];
  __shared__ unsigned wavePiv0[4], wavePiv1[4];
  __shared__ unsigned ccnt0, ccnt1;

  const int tid  = threadIdx.x;
  const int lane = tid & 63;
  const int wid  = tid >> 6;
  const int q0   = blockIdx.x * 2;      // two queries per block, same batch
  const int b    = q0 >> 11;            // / S (S = 2048)

  const float qx0 = new_xyz[q0 * 3 + 0];
  const float qy0 = new_xyz[q0 * 3 + 1];
  const float qz0 = new_xyz[q0 * 3 + 2];
  const float qx1 = new_xyz[q0 * 3 + 3];
  const float qy1 = new_xyz[q0 * 3 + 4];
  const float qz1 = new_xyz[q0 * 3 + 5];

  const float4* __restrict__ xb4 = (const float4*)(xyz + (size_t)b * Nc * 3);

  // ---- keys as NAMED uint4 SSA values (no array -> cannot go to scratch) --
  uint4 kA0, kA1, kA2, kA3, kA4, kA5, kA6, kA7;   // query 0, 32 keys
  uint4 kB0, kB1, kB2, kB3, kB4, kB5, kB6, kB7;   // query 1, 32 keys
  unsigned lmin0 = 0xFFFFFFFFu, lmin1 = 0xFFFFFFFFu;

#define DISTG(J2, KA, KB)                                                   \
  {                                                                         \
    const int g = tid + (J2) * THREADS;                                     \
    const float4 f0 = xb4[3 * g + 0];                                       \
    const float4 f1 = xb4[3 * g + 1];                                       \
    const float4 f2 = xb4[3 * g + 2];                                       \
    KA.x = dist2bits(qx0, qy0, qz0, f0.x, f0.y, f0.z);                      \
    KA.y = dist2bits(qx0, qy0, qz0, f0.w, f1.x, f1.y);                      \
    KA.z = dist2bits(qx0, qy0, qz0, f1.z, f1.w, f2.x);                      \
    KA.w = dist2bits(qx0, qy0, qz0, f2.y, f2.z, f2.w);                      \
    KB.x = dist2bits(qx1, qy1, qz1, f0.x, f0.y, f0.z);                      \
    KB.y = dist2bits(qx1, qy1, qz1, f0.w, f1.x, f1.y);                      \
    KB.z = dist2bits(qx1, qy1, qz1, f1.z, f1.w, f2.x);                      \
    KB.w = dist2bits(qx1, qy1, qz1, f2.y, f2.z, f2.w);                      \
    lmin0 = min(lmin0, min(min(KA.x, KA.y), min(KA.z, KA.w)));              \
    lmin1 = min(lmin1, min(min(KB.x, KB.y), min(KB.z, KB.w)));              \
  }

  DISTG(0, kA0, kB0)
  DISTG(1, kA1, kB1)
  DISTG(2, kA2, kB2)
  DISTG(3, kA3, kB3)
  DISTG(4, kA4, kB4)
  DISTG(5, kA5, kB5)
  DISTG(6, kA6, kB6)
  DISTG(7, kA7, kB7)
#undef DISTG

  // ---- per-wave 8th-smallest of 64 lane-mins via bitwise ballot select ----
  // largest P with count(lmin < P) < 8; pivot = P+1 -> >=8/wave -> >=32 block
  unsigned P0 = 0u, P1 = 0u;
#pragma unroll
  for (int bb = 30; bb >= 0; --bb) {
    const unsigned t0 = P0 | (1u << bb);
    const unsigned t1 = P1 | (1u << bb);
    if (__popcll(__ballot(lmin0 < t0)) < 8) P0 = t0;
    if (__popcll(__ballot(lmin1 < t1)) < 8) P1 = t1;
  }
  if (lane == 0) { wavePiv0[wid] = P0 + 1u; wavePiv1[wid] = P1 + 1u; }
  if (tid == 0) { ccnt0 = 0u; ccnt1 = 0u; }
  __syncthreads();

  unsigned piv0 = max(max(wavePiv0[0], wavePiv0[1]),
                      max(wavePiv0[2], wavePiv0[3]));
  unsigned piv1 = max(max(wavePiv1[0], wavePiv1[1]),
                      max(wavePiv1[2], wavePiv1[3]));

  // ---- compaction (pure register sweep); rare bisection retry ----
#define CHK0(V, PI)                                                         \
  if ((V) < piv0e) {                                                        \
    const unsigned pos = atomicAdd(&ccnt0, 1u);                             \
    if (pos < CAP) { candDb0[pos] = (V); candIdx0[pos] = (PI); }            \
  }
#define CHK1(V, PI)                                                         \
  if ((V) < piv1e) {                                                        \
    const unsigned pos = atomicAdd(&ccnt1, 1u);                             \
    if (pos < CAP) { candDb1[pos] = (V); candIdx1[pos] = (PI); }            \
  }
#define SWEEPG(J2, KA, KB)                                                  \
  {                                                                         \
    const unsigned base = 4u * (unsigned)(tid + (J2) * THREADS);            \
    CHK0(KA.x, base + 0) CHK0(KA.y, base + 1)                               \
    CHK0(KA.z, base + 2) CHK0(KA.w, base + 3)                               \
    CHK1(KB.x, base + 0) CHK1(KB.y, base + 1)                               \
    CHK1(KB.z, base + 2) CHK1(KB.w, base + 3)                               \
  }

  unsigned C0 = 0, C1 = 0;
  unsigned lo0 = 0u, hi0 = 0xFFFFFFFFu, lo1 = 0u, hi1 = 0xFFFFFFFFu;
  bool done0 = false, done1 = false, force0 = false, force1 = false;
  for (int it = 0; it < MAXRETRY; ++it) {
    const unsigned piv0e = done0 ? 0u : piv0;
    const unsigned piv1e = done1 ? 0u : piv1;
    SWEEPG(0, kA0, kB0)
    SWEEPG(1, kA1, kB1)
    SWEEPG(2, kA2, kB2)
    SWEEPG(3, kA3, kB3)
    SWEEPG(4, kA4, kB4)
    SWEEPG(5, kA5, kB5)
    SWEEPG(6, kA6, kB6)
    SWEEPG(7, kA7, kB7)
    __syncthreads();
    const unsigned c0 = ccnt0, c1 = ccnt1;   // block-uniform decisions
    if (!done0) {
      if (force0 || (c0 >= KNN && c0 <= CAP)) { C0 = min(c0, (unsigned)CAP); done0 = true; }
      else {
        if (c0 < KNN) lo0 = piv0; else hi0 = piv0;
        if (hi0 - lo0 <= 1u) { piv0 = hi0; force0 = true; }
        else piv0 = lo0 + ((hi0 - lo0) >> 1);
      }
    }
    if (!done1) {
      if (force1 || (c1 >= KNN && c1 <= CAP)) { C1 = min(c1, (unsigned)CAP); done1 = true; }
      else {
        if (c1 < KNN) lo1 = piv1; else hi1 = piv1;
        if (hi1 - lo1 <= 1u) { piv1 = hi1; force1 = true; }
        else piv1 = lo1 + ((hi1 - lo1) >> 1);
      }
    }
    if (done0 && done1) break;
    __syncthreads();
    if (tid == 0) { if (!done0) ccnt0 = 0u; if (!done1) ccnt1 = 0u; }
    __syncthreads();
  }
#undef SWEEPG
#undef CHK0
#undef CHK1

  // ---- sqrt only candidates (numpy ranks use sqrt f32 bits + idx ties) ----
  for (unsigned t = tid; t < C0; t += THREADS)
    candDb0[t] = __float_as_uint(__fsqrt_rn(__uint_as_float(candDb0[t])));
  for (unsigned t = tid; t < C1; t += THREADS)
    candDb1[t] = __float_as_uint(__fsqrt_rn(__uint_as_float(candDb1[t])));
  __syncthreads();

  // ---- exact rank by (sqrt bits, idx); C <= CAP -> ~1 candidate/thread ----
  for (unsigned t = tid; t < C0; t += THREADS) {
    const unsigned mdb = candDb0[t];
    const unsigned mix = candIdx0[t];
    unsigned rank = 0u;
    for (unsigned o = 0; o < C0; ++o) {   // same addr across lanes: broadcast
      const unsigned odb = candDb0[o];
      const unsigned oix = candIdx0[o];
      rank += (odb < mdb || (odb == mdb && oix < mix)) ? 1u : 0u;
    }
    if (rank < KNN) { winIdx0[rank] = mix; winDb0[rank] = mdb; }
  }
  for (unsigned t = tid; t < C1; t += THREADS) {
    const unsigned mdb = candDb1[t];
    const unsigned mix = candIdx1[t];
    unsigned rank = 0u;
    for (unsigned o = 0; o < C1; ++o) {
      const unsigned odb = candDb1[o];
      const unsigned oix = candIdx1[o];
      rank += (odb < mdb || (odb == mdb && oix < mix)) ? 1u : 0u;
    }
    if (rank < KNN) { winIdx1[rank] = mix; winDb1[rank] = mdb; }
  }
  __syncthreads();

  // ---- outputs (flat concat: nxyz | idxs | nfeat | values), all f32 ----
  float* out_nx = out;                                   // B*S*K*3
  float* out_id = out + (size_t)Bc * Sc * KNN * 3;       // B*S*K
  float* out_nf = out_id + (size_t)Bc * Sc * KNN;        // B*S*K*C
  float* out_sv = out_nf + (size_t)Bc * Sc * KNN * Cch;  // B*S*K

  const float* xb = xyz + (size_t)b * Nc * 3;
  const float4* fb4 = (const float4*)(feat + (size_t)b * Nc * Cch);

  if (tid < KNN * 2) {                  // idx + value, both queries
    const int qi = tid >> 5, w = tid & 31;
    const unsigned wi = qi ? winIdx1[w] : winIdx0[w];
    const unsigned wd = qi ? winDb1[w] : winDb0[w];
    out_id[(size_t)(q0 + qi) * KNN + w] = (float)wi;
    out_sv[(size_t)(q0 + qi) * KNN + w] = __uint_as_float(wd);
  }
  if (tid < KNN * 3 * 2) {              // neighbor xyz, both queries
    const int qi = tid / 96, r = tid % 96;
    const int w = r / 3, c3 = r % 3;
    const unsigned wi = qi ? winIdx1[w] : winIdx0[w];
    out_nx[((size_t)(q0 + qi) * KNN + w) * 3 + c3] =
        xb[(size_t)wi * 3 + c3];
  }
  // feature gather: per query 32 winners x 16 float4 = 512 -> 2 rounds each;
  // issue all 4 loads before the 4 stores (ILP over scattered L2 reads)
  {
    const int w0 = tid >> 4, c40 = tid & 15;
    const int w1 = (tid + THREADS) >> 4, c41 = tid & 15;
    float4* onf0 = (float4*)(out_nf + (size_t)q0 * KNN * Cch);
    float4* onf1 = (float4*)(out_nf + (size_t)(q0 + 1) * KNN * Cch);
    const float4 vA = fb4[(size_t)winIdx0[w0] * 16 + c40];
    const float4 vB = fb4[(size_t)winIdx0[w1] * 16 + c41];
    const float4 vC = fb4[(size_t)winIdx1[w0] * 16 + c40];
    const float4 vD = fb4[(size_t)winIdx1[w1] * 16 + c41];
    onf0[w0 * 16 + c40] = vA;
    onf0[w1 * 16 + c41] = vB;
    onf1[w0 * 16 + c40] = vC;
    onf1[w1 * 16 + c41] = vD;
  }
}

extern "C" void kernel_launch(void* const* d_in, const int* in_sizes, int n_in,
                              void* d_out, int out_size, void* d_ws, size_t ws_size,
                              hipStream_t stream) {
  const float* xyz     = (const float*)d_in[0];
  const float* new_xyz = (const float*)d_in[1];
  const float* feat    = (const float*)d_in[2];
  float* out = (float*)d_out;

  const int grid = (Bc * Sc) / 2;  // 4096 blocks, 2 queries each
  neighbor_group_kernel<<<grid, THREADS, 0, stream>>>(xyz, new_xyz, feat, out);
}